// Round 7
// baseline (617.875 us; speedup 1.0000x reference)
//
#include <hip/hip_runtime.h>
#include <cstdint>
#include <cstddef>

#define NB    2
#define N1    4096
#define N2    16384
#define CF    64
#define KNN   8
#define SPLIT 8
#define NS    (N1 / SPLIT)   // 512 candidates per split

// ---------------------------------------------------------------------------
// Scalarized stable top-8 insert (merge kernel): strict <, descending update
// order reading pre-update values -> lower index wins ties (= top_k).
// ---------------------------------------------------------------------------
#define TKDECL(P) \
    float P##d0=INFINITY,P##d1=INFINITY,P##d2=INFINITY,P##d3=INFINITY, \
          P##d4=INFINITY,P##d5=INFINITY,P##d6=INFINITY,P##d7=INFINITY; \
    int   P##i0=0,P##i1=0,P##i2=0,P##i3=0,P##i4=0,P##i5=0,P##i6=0,P##i7=0

#define TKINS(P, dv, ix) do { \
    const bool c0_ = (dv) < P##d0, c1_ = (dv) < P##d1, c2_ = (dv) < P##d2, c3_ = (dv) < P##d3; \
    const bool c4_ = (dv) < P##d4, c5_ = (dv) < P##d5, c6_ = (dv) < P##d6, c7_ = (dv) < P##d7; \
    P##d7 = c6_ ? P##d6 : (c7_ ? (dv) : P##d7);  P##i7 = c6_ ? P##i6 : (c7_ ? (ix) : P##i7); \
    P##d6 = c5_ ? P##d5 : (c6_ ? (dv) : P##d6);  P##i6 = c5_ ? P##i5 : (c6_ ? (ix) : P##i6); \
    P##d5 = c4_ ? P##d4 : (c5_ ? (dv) : P##d5);  P##i5 = c4_ ? P##i4 : (c5_ ? (ix) : P##i5); \
    P##d4 = c3_ ? P##d3 : (c4_ ? (dv) : P##d4);  P##i4 = c3_ ? P##i3 : (c4_ ? (ix) : P##i4); \
    P##d3 = c2_ ? P##d2 : (c3_ ? (dv) : P##d3);  P##i3 = c2_ ? P##i2 : (c3_ ? (ix) : P##i3); \
    P##d2 = c1_ ? P##d1 : (c2_ ? (dv) : P##d2);  P##i2 = c1_ ? P##i1 : (c2_ ? (ix) : P##i2); \
    P##d1 = c0_ ? P##d0 : (c1_ ? (dv) : P##d1);  P##i1 = c0_ ? P##i0 : (c1_ ? (ix) : P##i1); \
    P##d0 = c0_ ? (dv) : P##d0;                  P##i0 = c0_ ? (ix) : P##i0; \
} while (0)

// ---------------------------------------------------------------------------
// kernel 0: transpose feat1 [B,C,N1] -> feat1T [B,N1,C]; pack xyz1/flow float4
// ---------------------------------------------------------------------------
__global__ __launch_bounds__(256, 2) void k_pack(
    const float* __restrict__ xyz1, const float* __restrict__ feat1,
    const float* __restrict__ flow,
    float* __restrict__ feat1T, float4* __restrict__ aux4,
    float4* __restrict__ flow4)
{
    __shared__ float tile[64][65];
    const int b  = blockIdx.y;
    const int n0 = blockIdx.x * 64;
    const int tid = threadIdx.x;
    const int nl = tid & 63, cq = tid >> 6;

#pragma unroll
    for (int r = 0; r < 16; ++r) {
        const int c = r * 4 + cq;
        tile[c][nl] = feat1[((size_t)(b * CF + c)) * N1 + n0 + nl];
    }
    __syncthreads();
#pragma unroll
    for (int r = 0; r < 16; ++r) {
        const int nn = r * 4 + cq;
        feat1T[((size_t)(b * N1 + n0 + nn)) * CF + nl] = tile[nl][nn];
    }
    if (tid < 64) {
        const int n = n0 + tid;
        const float x = xyz1[(b * 3 + 0) * N1 + n];
        const float y = xyz1[(b * 3 + 1) * N1 + n];
        const float z = xyz1[(b * 3 + 2) * N1 + n];
        aux4[b * N1 + n] = make_float4(x, y, z, 0.f);
        const float fx = flow[(b * 3 + 0) * N1 + n];
        const float fy = flow[(b * 3 + 1) * N1 + n];
        const float fz = flow[(b * 3 + 2) * N1 + n];
        flow4[b * N1 + n] = make_float4(fx, fy, fz, 0.f);
    }
}

// ---------------------------------------------------------------------------
// kernel 1: partial KNN — QPT=2, SPLIT=8, branchless; med3 distance network
// (unchanged from R6; beat R5's gated variant). Distance replicates reference
// fp32 rounding exactly: d = (q2+t2) - (qt+qt), qt = ((qx*tx+qy*ty)+qz*tz).
// ---------------------------------------------------------------------------
__global__ __launch_bounds__(256, 2) void k_knn4(
    const float* __restrict__ xyz1, const float* __restrict__ xyz2,
    float* __restrict__ partd, int* __restrict__ parti)
{
    __shared__ float4 pts[NS];  // {x, y, z, t2} — 8 KiB
    const int sp  = blockIdx.y;
    const int tid = threadIdx.x;
    const int q0  = blockIdx.x * 512 + tid;
    const int q1  = q0 + 256;
    const int b   = q0 >> 14;    // uniform per block (512 | 16384)

    for (int t = tid; t < NS; t += 256) {
        const int jg = sp * NS + t;
        const float x = xyz1[(b * 3 + 0) * N1 + jg];
        const float y = xyz1[(b * 3 + 1) * N1 + jg];
        const float z = xyz1[(b * 3 + 2) * N1 + jg];
        const float t2 = __fadd_rn(__fadd_rn(__fmul_rn(x, x), __fmul_rn(y, y)),
                                   __fmul_rn(z, z));
        pts[t] = make_float4(x, y, z, t2);
    }
    __syncthreads();

    const int n0 = q0 & (N2 - 1), n1 = n0 + 256;
    const float ax = xyz2[(b * 3 + 0) * N2 + n0];
    const float ay = xyz2[(b * 3 + 1) * N2 + n0];
    const float az = xyz2[(b * 3 + 2) * N2 + n0];
    const float a2 = __fadd_rn(__fadd_rn(__fmul_rn(ax, ax), __fmul_rn(ay, ay)),
                               __fmul_rn(az, az));
    const float cx = xyz2[(b * 3 + 0) * N2 + n1];
    const float cy = xyz2[(b * 3 + 1) * N2 + n1];
    const float cz = xyz2[(b * 3 + 2) * N2 + n1];
    const float c2 = __fadd_rn(__fadd_rn(__fmul_rn(cx, cx), __fmul_rn(cy, cy)),
                               __fmul_rn(cz, cz));

    float Ad0=INFINITY,Ad1=INFINITY,Ad2=INFINITY,Ad3=INFINITY,
          Ad4=INFINITY,Ad5=INFINITY,Ad6=INFINITY,Ad7=INFINITY;
    int   Ai0=0,Ai1=0,Ai2=0,Ai3=0,Ai4=0,Ai5=0,Ai6=0,Ai7=0;
    float Bd0=INFINITY,Bd1=INFINITY,Bd2=INFINITY,Bd3=INFINITY,
          Bd4=INFINITY,Bd5=INFINITY,Bd6=INFINITY,Bd7=INFINITY;
    int   Bi0=0,Bi1=0,Bi2=0,Bi3=0,Bi4=0,Bi5=0,Bi6=0,Bi7=0;

#pragma unroll 4
    for (int j = 0; j < NS; ++j) {
        const float4 p = pts[j];
        const int idx = sp * NS + j;

        const float qtA = __fadd_rn(
            __fadd_rn(__fmul_rn(ax, p.x), __fmul_rn(ay, p.y)),
            __fmul_rn(az, p.z));
        const float dA = __fsub_rn(__fadd_rn(a2, p.w), __fadd_rn(qtA, qtA));
        const float qtB = __fadd_rn(
            __fadd_rn(__fmul_rn(cx, p.x), __fmul_rn(cy, p.y)),
            __fmul_rn(cz, p.z));
        const float dB = __fsub_rn(__fadd_rn(c2, p.w), __fadd_rn(qtB, qtB));

        {
            const float m0 = fminf(dA, Ad0);
            const float m1 = __builtin_amdgcn_fmed3f(dA, Ad0, Ad1);
            const float m2 = __builtin_amdgcn_fmed3f(dA, Ad1, Ad2);
            const float m3 = __builtin_amdgcn_fmed3f(dA, Ad2, Ad3);
            const float m4 = __builtin_amdgcn_fmed3f(dA, Ad3, Ad4);
            const float m5 = __builtin_amdgcn_fmed3f(dA, Ad4, Ad5);
            const float m6 = __builtin_amdgcn_fmed3f(dA, Ad5, Ad6);
            const float m7 = __builtin_amdgcn_fmed3f(dA, Ad6, Ad7);
            const bool a0 = dA < Ad0, a1 = dA < Ad1, a2c = dA < Ad2, a3 = dA < Ad3;
            const bool a4 = dA < Ad4, a5 = dA < Ad5, a6 = dA < Ad6, a7 = dA < Ad7;
            Ai7 = a6 ? Ai6 : (a7 ? idx : Ai7);
            Ai6 = a5 ? Ai5 : (a6 ? idx : Ai6);
            Ai5 = a4 ? Ai4 : (a5 ? idx : Ai5);
            Ai4 = a3 ? Ai3 : (a4 ? idx : Ai4);
            Ai3 = a2c ? Ai2 : (a3 ? idx : Ai3);
            Ai2 = a1 ? Ai1 : (a2c ? idx : Ai2);
            Ai1 = a0 ? Ai0 : (a1 ? idx : Ai1);
            Ai0 = a0 ? idx : Ai0;
            Ad0=m0; Ad1=m1; Ad2=m2; Ad3=m3; Ad4=m4; Ad5=m5; Ad6=m6; Ad7=m7;
        }
        {
            const float m0 = fminf(dB, Bd0);
            const float m1 = __builtin_amdgcn_fmed3f(dB, Bd0, Bd1);
            const float m2 = __builtin_amdgcn_fmed3f(dB, Bd1, Bd2);
            const float m3 = __builtin_amdgcn_fmed3f(dB, Bd2, Bd3);
            const float m4 = __builtin_amdgcn_fmed3f(dB, Bd3, Bd4);
            const float m5 = __builtin_amdgcn_fmed3f(dB, Bd4, Bd5);
            const float m6 = __builtin_amdgcn_fmed3f(dB, Bd5, Bd6);
            const float m7 = __builtin_amdgcn_fmed3f(dB, Bd6, Bd7);
            const bool a0 = dB < Bd0, a1 = dB < Bd1, a2c = dB < Bd2, a3 = dB < Bd3;
            const bool a4 = dB < Bd4, a5 = dB < Bd5, a6 = dB < Bd6, a7 = dB < Bd7;
            Bi7 = a6 ? Bi6 : (a7 ? idx : Bi7);
            Bi6 = a5 ? Bi5 : (a6 ? idx : Bi6);
            Bi5 = a4 ? Bi4 : (a5 ? idx : Bi5);
            Bi4 = a3 ? Bi3 : (a4 ? idx : Bi4);
            Bi3 = a2c ? Bi2 : (a3 ? idx : Bi3);
            Bi2 = a1 ? Bi1 : (a2c ? idx : Bi2);
            Bi1 = a0 ? Bi0 : (a1 ? idx : Bi1);
            Bi0 = a0 ? idx : Bi0;
            Bd0=m0; Bd1=m1; Bd2=m2; Bd3=m3; Bd4=m4; Bd5=m5; Bd6=m6; Bd7=m7;
        }
    }

    {
        float* pd = partd + ((size_t)q0 * SPLIT + sp) * KNN;
        int*   pi = parti + ((size_t)q0 * SPLIT + sp) * KNN;
        pd[0]=Ad0; pd[1]=Ad1; pd[2]=Ad2; pd[3]=Ad3; pd[4]=Ad4; pd[5]=Ad5; pd[6]=Ad6; pd[7]=Ad7;
        pi[0]=Ai0; pi[1]=Ai1; pi[2]=Ai2; pi[3]=Ai3; pi[4]=Ai4; pi[5]=Ai5; pi[6]=Ai6; pi[7]=Ai7;
    }
    {
        float* pd = partd + ((size_t)q1 * SPLIT + sp) * KNN;
        int*   pi = parti + ((size_t)q1 * SPLIT + sp) * KNN;
        pd[0]=Bd0; pd[1]=Bd1; pd[2]=Bd2; pd[3]=Bd3; pd[4]=Bd4; pd[5]=Bd5; pd[6]=Bd6; pd[7]=Bd7;
        pi[0]=Bi0; pi[1]=Bi1; pi[2]=Bi2; pi[3]=Bi3; pi[4]=Bi4; pi[5]=Bi5; pi[6]=Bi6; pi[7]=Bi7;
    }
}

// ---------------------------------------------------------------------------
// kernel 2: merge SPLIT partial top-8 lists (ascending split order -> stable)
// ---------------------------------------------------------------------------
__global__ __launch_bounds__(256, 2) void k_merge2(
    const float* __restrict__ partd, const int* __restrict__ parti,
    int* __restrict__ knn_idx)
{
    const int q = blockIdx.x * 256 + threadIdx.x;
    const float* pd = partd + (size_t)q * SPLIT * KNN;
    const int*   pi = parti + (size_t)q * SPLIT * KNN;

    TKDECL(M);
#pragma unroll
    for (int t = 0; t < SPLIT * KNN; ++t) {
        const float d = pd[t];
        const int   i = pi[t];
        TKINS(M, d, i);
    }
    int* ko = knn_idx + (size_t)q * KNN;
    ko[0]=Mi0; ko[1]=Mi1; ko[2]=Mi2; ko[3]=Mi3; ko[4]=Mi4; ko[5]=Mi5; ko[6]=Mi6; ko[7]=Mi7;
}

// ---------------------------------------------------------------------------
// kernel 3: MLP — 4 independent waves per block SHARING one w1s copy (fixes
// R6's LDS-capped 8 waves/CU). One __syncthreads after the w1s load; after
// that waves never sync: each exchanges data only among its own 64 lanes via
// private inbuf[wave], safe via the per-wave in-order DS pipe
// (wave_barrier pins compiler ordering, no HW cost). QPW=8, 2-deep id
// pipeline, gathers prefetched one query ahead. Math identical to R6.
// ---------------------------------------------------------------------------
#define ACC4(h, wv, iv) \
    h = fmaf((wv).x, (iv).x, h); h = fmaf((wv).y, (iv).y, h); \
    h = fmaf((wv).z, (iv).z, h); h = fmaf((wv).w, (iv).w, h)

#define DOT17(h, ivr) do { \
    ACC4(h, w0,  (ivr)[0]);  ACC4(h, w1,  (ivr)[1]);  ACC4(h, w2,  (ivr)[2]); \
    ACC4(h, w3,  (ivr)[3]);  ACC4(h, w4,  (ivr)[4]);  ACC4(h, w5,  (ivr)[5]); \
    ACC4(h, w6,  (ivr)[6]);  ACC4(h, w7,  (ivr)[7]);  ACC4(h, w8,  (ivr)[8]); \
    ACC4(h, w9,  (ivr)[9]);  ACC4(h, w10, (ivr)[10]); ACC4(h, w11, (ivr)[11]); \
    ACC4(h, w12, (ivr)[12]); ACC4(h, w13, (ivr)[13]); ACC4(h, w14, (ivr)[14]); \
    ACC4(h, w15, (ivr)[15]); ACC4(h, w16, (ivr)[16]); \
} while (0)

#define BFLY(p) \
    p += __shfl_xor(p, 32, 64); p += __shfl_xor(p, 16, 64); \
    p += __shfl_xor(p,  8, 64); p += __shfl_xor(p,  4, 64); \
    p += __shfl_xor(p,  2, 64); p += __shfl_xor(p,  1, 64)

#define L2RED(hk, a0, a1, a2) do { \
    float hv_ = (hk); hv_ = hv_ >= 0.f ? hv_ : 0.1f * hv_; \
    float p0_ = w2a * hv_, p1_ = w2b * hv_, p2_ = w2c * hv_; \
    BFLY(p0_); BFLY(p1_); BFLY(p2_); \
    a0 = p0_ + b20; a1 = p1_ + b21; a2 = p2_ + b22; \
} while (0)

#define SMAX8(sa, sb, sc, sd, se, sf, sg, sh, CH, res) do { \
    const float m_ = fmaxf(fmaxf(fmaxf(sa, sb), fmaxf(sc, sd)), \
                           fmaxf(fmaxf(se, sf), fmaxf(sg, sh))); \
    const float e0_ = __expf(sa - m_), e1_ = __expf(sb - m_); \
    const float e2_ = __expf(sc - m_), e3_ = __expf(sd - m_); \
    const float e4_ = __expf(se - m_), e5_ = __expf(sf - m_); \
    const float e6_ = __expf(sg - m_), e7_ = __expf(sh - m_); \
    const float S_ = ((e0_ + e1_) + (e2_ + e3_)) + ((e4_ + e5_) + (e6_ + e7_)); \
    float acc_ = e0_ * flf[0 * 4 + CH]; \
    acc_ = fmaf(e1_, flf[1 * 4 + CH], acc_); acc_ = fmaf(e2_, flf[2 * 4 + CH], acc_); \
    acc_ = fmaf(e3_, flf[3 * 4 + CH], acc_); acc_ = fmaf(e4_, flf[4 * 4 + CH], acc_); \
    acc_ = fmaf(e5_, flf[5 * 4 + CH], acc_); acc_ = fmaf(e6_, flf[6 * 4 + CH], acc_); \
    acc_ = fmaf(e7_, flf[7 * 4 + CH], acc_); \
    res = acc_ / S_; \
} while (0)

#define MLP_STEP(IT) do { \
    const int n_ = n0 + (IT); \
    __builtin_amdgcn_wave_barrier();  /* WAR: prev-iter reads precede writes */ \
    float4* drow = (float4*)(inw + k * 68); \
    drow[p * 2] = g0; drow[p * 2 + 1] = g1; \
    if (p == 0) { \
        inw[k * 68 + 64] = axv.x - qx; inw[k * 68 + 65] = axv.y - qy; \
        inw[k * 68 + 66] = axv.z - qz; inw[k * 68 + 67] = 0.f; \
    } \
    if (p == 1) flbuf[wave][k] = flv; \
    __builtin_amdgcn_wave_barrier();  /* RAW: writes precede this iter's reads */ \
    if ((IT) < 7) {   /* prefetch next query's gather under this compute */ \
        const int idn_ = idnext; \
        const float4* fr_ = (const float4*)(feat1T + (size_t)(base + idn_) * CF); \
        g0 = fr_[p * 2]; g1 = fr_[p * 2 + 1]; \
        axv = aux4[base + idn_]; flv = flow4[base + idn_]; \
        qx = xyz2[(b * 3 + 0) * N2 + n_ + 1]; \
        qy = xyz2[(b * 3 + 1) * N2 + n_ + 1]; \
        qz = xyz2[(b * 3 + 2) * N2 + n_ + 1]; \
        if ((IT) < 6) idnext = knn_idx[(size_t)(q0 + (IT) + 2) * KNN + k]; \
    } \
    float s00, s01, s02, s03, s04, s05, s06, s07; \
    float s10, s11, s12, s13, s14, s15, s16, s17; \
    float s20, s21, s22, s23, s24, s25, s26, s27; \
    { float h = b1v; DOT17(h, ((const float4*)(inw + 0 * 68))); L2RED(h, s00, s10, s20); } \
    { float h = b1v; DOT17(h, ((const float4*)(inw + 1 * 68))); L2RED(h, s01, s11, s21); } \
    { float h = b1v; DOT17(h, ((const float4*)(inw + 2 * 68))); L2RED(h, s02, s12, s22); } \
    { float h = b1v; DOT17(h, ((const float4*)(inw + 3 * 68))); L2RED(h, s03, s13, s23); } \
    { float h = b1v; DOT17(h, ((const float4*)(inw + 4 * 68))); L2RED(h, s04, s14, s24); } \
    { float h = b1v; DOT17(h, ((const float4*)(inw + 5 * 68))); L2RED(h, s05, s15, s25); } \
    { float h = b1v; DOT17(h, ((const float4*)(inw + 6 * 68))); L2RED(h, s06, s16, s26); } \
    { float h = b1v; DOT17(h, ((const float4*)(inw + 7 * 68))); L2RED(h, s07, s17, s27); } \
    float res0, res1, res2; \
    SMAX8(s00, s01, s02, s03, s04, s05, s06, s07, 0, res0); \
    SMAX8(s10, s11, s12, s13, s14, s15, s16, s17, 1, res1); \
    SMAX8(s20, s21, s22, s23, s24, s25, s26, s27, 2, res2); \
    const float resv = lane == 0 ? res0 : (lane == 1 ? res1 : res2); \
    if (lane < 3) out[((size_t)(b * 3 + lane)) * N2 + n_] = resv; \
} while (0)

__global__ __launch_bounds__(256, 4) void k_mlp3(
    const float* __restrict__ feat1T, const float4* __restrict__ aux4,
    const float4* __restrict__ flow4, const int* __restrict__ knn_idx,
    const float* __restrict__ xyz2,
    const float* __restrict__ W1, const float* __restrict__ b1,
    const float* __restrict__ W2, const float* __restrict__ b2,
    float* __restrict__ out)
{
    __shared__ __align__(16) float w1s[64 * 68];     // 17.0 KiB, shared by 4 waves
    __shared__ __align__(16) float inbuf[4][8][68];  //  8.5 KiB, private per wave
    __shared__ __align__(16) float4 flbuf[4][8];     //  0.5 KiB, private per wave

    const int tid  = threadIdx.x;
    const int wave = tid >> 6, lane = tid & 63;

    for (int t = tid; t < 64 * 67; t += 256) {
        const int o = t / 67, c = t - o * 67;
        w1s[o * 68 + c] = W1[t];
    }
    if (tid < 64) w1s[tid * 68 + 67] = 0.f;

    const float b1v = b1[lane];
    const float w2a = W2[lane], w2b = W2[64 + lane], w2c = W2[128 + lane];
    const float b20 = b2[0], b21 = b2[1], b22 = b2[2];
    __syncthreads();   // the ONLY cross-wave barrier

    const float4* wr = (const float4*)&w1s[lane * 68];
    const float4 w0 = wr[0],  w1 = wr[1],  w2 = wr[2],  w3 = wr[3];
    const float4 w4 = wr[4],  w5 = wr[5],  w6 = wr[6],  w7 = wr[7];
    const float4 w8 = wr[8],  w9 = wr[9],  w10 = wr[10], w11 = wr[11];
    const float4 w12 = wr[12], w13 = wr[13], w14 = wr[14], w15 = wr[15];
    const float4 w16 = wr[16];

    const int k = lane >> 3, p = lane & 7;
    float* inw = &inbuf[wave][0][0];
    const float* flf = (const float*)&flbuf[wave][0];

    const int q0   = blockIdx.x * 32 + wave * 8;   // 8 queries per wave
    const int b    = q0 >> 14;                      // uniform (32 | 16384)
    const int base = b * N1;
    const int n0   = q0 & (N2 - 1);

    // id pipeline: idcur for iter 0, idnext for iter 1
    const int id0v = knn_idx[(size_t)q0 * KNN + k];
    int idnext     = knn_idx[(size_t)(q0 + 1) * KNN + k];

    // stage iteration 0
    const float4* fr0 = (const float4*)(feat1T + (size_t)(base + id0v) * CF);
    float4 g0 = fr0[p * 2], g1 = fr0[p * 2 + 1];
    float4 axv = aux4[base + id0v];
    float4 flv = flow4[base + id0v];
    float qx = xyz2[(b * 3 + 0) * N2 + n0];
    float qy = xyz2[(b * 3 + 1) * N2 + n0];
    float qz = xyz2[(b * 3 + 2) * N2 + n0];

    MLP_STEP(0);
    MLP_STEP(1);
    MLP_STEP(2);
    MLP_STEP(3);
    MLP_STEP(4);
    MLP_STEP(5);
    MLP_STEP(6);
    MLP_STEP(7);
}

// ---------------------------------------------------------------------------
extern "C" void kernel_launch(void* const* d_in, const int* in_sizes, int n_in,
                              void* d_out, int out_size, void* d_ws, size_t ws_size,
                              hipStream_t stream)
{
    const float* xyz1  = (const float*)d_in[0];
    const float* xyz2  = (const float*)d_in[1];
    const float* feat1 = (const float*)d_in[2];
    const float* flow  = (const float*)d_in[3];
    const float* W1    = (const float*)d_in[4];
    const float* b1    = (const float*)d_in[5];
    const float* W2    = (const float*)d_in[6];
    const float* b2    = (const float*)d_in[7];
    float* out = (float*)d_out;

    char* ws = (char*)d_ws;
    float*  feat1T  = (float*)(ws);                                   // 2 MiB
    float4* aux4    = (float4*)(ws + (2u << 20));                     // 128 KiB
    float4* flow4   = (float4*)(ws + (2u << 20) + (128u << 10));      // 128 KiB
    int*    knn_idx = (int*)  (ws + (2u << 20) + (256u << 10));       // 1 MiB
    float*  partd   = (float*)(ws + (3u << 20) + (256u << 10));       // 8 MiB
    int*    parti   = (int*)  (ws + (11u << 20) + (256u << 10));      // 8 MiB

    hipLaunchKernelGGL(k_pack, dim3(N1 / 64, NB), dim3(256), 0, stream,
                       xyz1, feat1, flow, feat1T, aux4, flow4);
    hipLaunchKernelGGL(k_knn4, dim3(NB * N2 / 512, SPLIT), dim3(256), 0, stream,
                       xyz1, xyz2, partd, parti);
    hipLaunchKernelGGL(k_merge2, dim3(NB * N2 / 256), dim3(256), 0, stream,
                       partd, parti, knn_idx);
    hipLaunchKernelGGL(k_mlp3, dim3(NB * N2 / 32), dim3(256), 0, stream,
                       feat1T, aux4, flow4, knn_idx, xyz2, W1, b1, W2, b2, out);
}

// Round 8
// 345.952 us; speedup vs baseline: 1.7860x; 1.7860x over previous
//
#include <hip/hip_runtime.h>
#include <cstdint>
#include <cstddef>

#define NB    2
#define N1    4096
#define N2    16384
#define CF    64
#define KNN   8
#define SPLIT 8
#define NS    (N1 / SPLIT)   // 512 candidates per split

// ---------------------------------------------------------------------------
// Scalarized stable top-8 insert (merge kernel): strict <, descending update
// order reading pre-update values -> lower index wins ties (= top_k).
// ---------------------------------------------------------------------------
#define TKDECL(P) \
    float P##d0=INFINITY,P##d1=INFINITY,P##d2=INFINITY,P##d3=INFINITY, \
          P##d4=INFINITY,P##d5=INFINITY,P##d6=INFINITY,P##d7=INFINITY; \
    int   P##i0=0,P##i1=0,P##i2=0,P##i3=0,P##i4=0,P##i5=0,P##i6=0,P##i7=0

#define TKINS(P, dv, ix) do { \
    const bool c0_ = (dv) < P##d0, c1_ = (dv) < P##d1, c2_ = (dv) < P##d2, c3_ = (dv) < P##d3; \
    const bool c4_ = (dv) < P##d4, c5_ = (dv) < P##d5, c6_ = (dv) < P##d6, c7_ = (dv) < P##d7; \
    P##d7 = c6_ ? P##d6 : (c7_ ? (dv) : P##d7);  P##i7 = c6_ ? P##i6 : (c7_ ? (ix) : P##i7); \
    P##d6 = c5_ ? P##d5 : (c6_ ? (dv) : P##d6);  P##i6 = c5_ ? P##i5 : (c6_ ? (ix) : P##i6); \
    P##d5 = c4_ ? P##d4 : (c5_ ? (dv) : P##d5);  P##i5 = c4_ ? P##i4 : (c5_ ? (ix) : P##i5); \
    P##d4 = c3_ ? P##d3 : (c4_ ? (dv) : P##d4);  P##i4 = c3_ ? P##i3 : (c4_ ? (ix) : P##i4); \
    P##d3 = c2_ ? P##d2 : (c3_ ? (dv) : P##d3);  P##i3 = c2_ ? P##i2 : (c3_ ? (ix) : P##i3); \
    P##d2 = c1_ ? P##d1 : (c2_ ? (dv) : P##d2);  P##i2 = c1_ ? P##i1 : (c2_ ? (ix) : P##i2); \
    P##d1 = c0_ ? P##d0 : (c1_ ? (dv) : P##d1);  P##i1 = c0_ ? P##i0 : (c1_ ? (ix) : P##i1); \
    P##d0 = c0_ ? (dv) : P##d0;                  P##i0 = c0_ ? (ix) : P##i0; \
} while (0)

// ---------------------------------------------------------------------------
// kernel 0: transpose feat1 [B,C,N1] -> feat1T [B,N1,C]; pack xyz1/flow float4
// ---------------------------------------------------------------------------
__global__ __launch_bounds__(256, 2) void k_pack(
    const float* __restrict__ xyz1, const float* __restrict__ feat1,
    const float* __restrict__ flow,
    float* __restrict__ feat1T, float4* __restrict__ aux4,
    float4* __restrict__ flow4)
{
    __shared__ float tile[64][65];
    const int b  = blockIdx.y;
    const int n0 = blockIdx.x * 64;
    const int tid = threadIdx.x;
    const int nl = tid & 63, cq = tid >> 6;

#pragma unroll
    for (int r = 0; r < 16; ++r) {
        const int c = r * 4 + cq;
        tile[c][nl] = feat1[((size_t)(b * CF + c)) * N1 + n0 + nl];
    }
    __syncthreads();
#pragma unroll
    for (int r = 0; r < 16; ++r) {
        const int nn = r * 4 + cq;
        feat1T[((size_t)(b * N1 + n0 + nn)) * CF + nl] = tile[nl][nn];
    }
    if (tid < 64) {
        const int n = n0 + tid;
        const float x = xyz1[(b * 3 + 0) * N1 + n];
        const float y = xyz1[(b * 3 + 1) * N1 + n];
        const float z = xyz1[(b * 3 + 2) * N1 + n];
        aux4[b * N1 + n] = make_float4(x, y, z, 0.f);
        const float fx = flow[(b * 3 + 0) * N1 + n];
        const float fy = flow[(b * 3 + 1) * N1 + n];
        const float fz = flow[(b * 3 + 2) * N1 + n];
        flow4[b * N1 + n] = make_float4(fx, fy, fz, 0.f);
    }
}

// ---------------------------------------------------------------------------
// kernel 1: partial KNN — QPT=2, SPLIT=8, branchless; med3 distance network.
// Distance replicates reference fp32 rounding exactly:
// d = (q2+t2) - (qt+qt), qt = ((qx*tx+qy*ty)+qz*tz), all _rn.
// ---------------------------------------------------------------------------
__global__ __launch_bounds__(256, 2) void k_knn4(
    const float* __restrict__ xyz1, const float* __restrict__ xyz2,
    float* __restrict__ partd, int* __restrict__ parti)
{
    __shared__ float4 pts[NS];  // {x, y, z, t2} — 8 KiB
    const int sp  = blockIdx.y;
    const int tid = threadIdx.x;
    const int q0  = blockIdx.x * 512 + tid;
    const int q1  = q0 + 256;
    const int b   = q0 >> 14;    // uniform per block (512 | 16384)

    for (int t = tid; t < NS; t += 256) {
        const int jg = sp * NS + t;
        const float x = xyz1[(b * 3 + 0) * N1 + jg];
        const float y = xyz1[(b * 3 + 1) * N1 + jg];
        const float z = xyz1[(b * 3 + 2) * N1 + jg];
        const float t2 = __fadd_rn(__fadd_rn(__fmul_rn(x, x), __fmul_rn(y, y)),
                                   __fmul_rn(z, z));
        pts[t] = make_float4(x, y, z, t2);
    }
    __syncthreads();

    const int n0 = q0 & (N2 - 1), n1 = n0 + 256;
    const float ax = xyz2[(b * 3 + 0) * N2 + n0];
    const float ay = xyz2[(b * 3 + 1) * N2 + n0];
    const float az = xyz2[(b * 3 + 2) * N2 + n0];
    const float a2 = __fadd_rn(__fadd_rn(__fmul_rn(ax, ax), __fmul_rn(ay, ay)),
                               __fmul_rn(az, az));
    const float cx = xyz2[(b * 3 + 0) * N2 + n1];
    const float cy = xyz2[(b * 3 + 1) * N2 + n1];
    const float cz = xyz2[(b * 3 + 2) * N2 + n1];
    const float c2 = __fadd_rn(__fadd_rn(__fmul_rn(cx, cx), __fmul_rn(cy, cy)),
                               __fmul_rn(cz, cz));

    float Ad0=INFINITY,Ad1=INFINITY,Ad2=INFINITY,Ad3=INFINITY,
          Ad4=INFINITY,Ad5=INFINITY,Ad6=INFINITY,Ad7=INFINITY;
    int   Ai0=0,Ai1=0,Ai2=0,Ai3=0,Ai4=0,Ai5=0,Ai6=0,Ai7=0;
    float Bd0=INFINITY,Bd1=INFINITY,Bd2=INFINITY,Bd3=INFINITY,
          Bd4=INFINITY,Bd5=INFINITY,Bd6=INFINITY,Bd7=INFINITY;
    int   Bi0=0,Bi1=0,Bi2=0,Bi3=0,Bi4=0,Bi5=0,Bi6=0,Bi7=0;

#pragma unroll 4
    for (int j = 0; j < NS; ++j) {
        const float4 p = pts[j];
        const int idx = sp * NS + j;

        const float qtA = __fadd_rn(
            __fadd_rn(__fmul_rn(ax, p.x), __fmul_rn(ay, p.y)),
            __fmul_rn(az, p.z));
        const float dA = __fsub_rn(__fadd_rn(a2, p.w), __fadd_rn(qtA, qtA));
        const float qtB = __fadd_rn(
            __fadd_rn(__fmul_rn(cx, p.x), __fmul_rn(cy, p.y)),
            __fmul_rn(cz, p.z));
        const float dB = __fsub_rn(__fadd_rn(c2, p.w), __fadd_rn(qtB, qtB));

        {
            const float m0 = fminf(dA, Ad0);
            const float m1 = __builtin_amdgcn_fmed3f(dA, Ad0, Ad1);
            const float m2 = __builtin_amdgcn_fmed3f(dA, Ad1, Ad2);
            const float m3 = __builtin_amdgcn_fmed3f(dA, Ad2, Ad3);
            const float m4 = __builtin_amdgcn_fmed3f(dA, Ad3, Ad4);
            const float m5 = __builtin_amdgcn_fmed3f(dA, Ad4, Ad5);
            const float m6 = __builtin_amdgcn_fmed3f(dA, Ad5, Ad6);
            const float m7 = __builtin_amdgcn_fmed3f(dA, Ad6, Ad7);
            const bool a0 = dA < Ad0, a1 = dA < Ad1, a2c = dA < Ad2, a3 = dA < Ad3;
            const bool a4 = dA < Ad4, a5 = dA < Ad5, a6 = dA < Ad6, a7 = dA < Ad7;
            Ai7 = a6 ? Ai6 : (a7 ? idx : Ai7);
            Ai6 = a5 ? Ai5 : (a6 ? idx : Ai6);
            Ai5 = a4 ? Ai4 : (a5 ? idx : Ai5);
            Ai4 = a3 ? Ai3 : (a4 ? idx : Ai4);
            Ai3 = a2c ? Ai2 : (a3 ? idx : Ai3);
            Ai2 = a1 ? Ai1 : (a2c ? idx : Ai2);
            Ai1 = a0 ? Ai0 : (a1 ? idx : Ai1);
            Ai0 = a0 ? idx : Ai0;
            Ad0=m0; Ad1=m1; Ad2=m2; Ad3=m3; Ad4=m4; Ad5=m5; Ad6=m6; Ad7=m7;
        }
        {
            const float m0 = fminf(dB, Bd0);
            const float m1 = __builtin_amdgcn_fmed3f(dB, Bd0, Bd1);
            const float m2 = __builtin_amdgcn_fmed3f(dB, Bd1, Bd2);
            const float m3 = __builtin_amdgcn_fmed3f(dB, Bd2, Bd3);
            const float m4 = __builtin_amdgcn_fmed3f(dB, Bd3, Bd4);
            const float m5 = __builtin_amdgcn_fmed3f(dB, Bd4, Bd5);
            const float m6 = __builtin_amdgcn_fmed3f(dB, Bd5, Bd6);
            const float m7 = __builtin_amdgcn_fmed3f(dB, Bd6, Bd7);
            const bool a0 = dB < Bd0, a1 = dB < Bd1, a2c = dB < Bd2, a3 = dB < Bd3;
            const bool a4 = dB < Bd4, a5 = dB < Bd5, a6 = dB < Bd6, a7 = dB < Bd7;
            Bi7 = a6 ? Bi6 : (a7 ? idx : Bi7);
            Bi6 = a5 ? Bi5 : (a6 ? idx : Bi6);
            Bi5 = a4 ? Bi4 : (a5 ? idx : Bi5);
            Bi4 = a3 ? Bi3 : (a4 ? idx : Bi4);
            Bi3 = a2c ? Bi2 : (a3 ? idx : Bi3);
            Bi2 = a1 ? Bi1 : (a2c ? idx : Bi2);
            Bi1 = a0 ? Bi0 : (a1 ? idx : Bi1);
            Bi0 = a0 ? idx : Bi0;
            Bd0=m0; Bd1=m1; Bd2=m2; Bd3=m3; Bd4=m4; Bd5=m5; Bd6=m6; Bd7=m7;
        }
    }

    {
        float* pd = partd + ((size_t)q0 * SPLIT + sp) * KNN;
        int*   pi = parti + ((size_t)q0 * SPLIT + sp) * KNN;
        pd[0]=Ad0; pd[1]=Ad1; pd[2]=Ad2; pd[3]=Ad3; pd[4]=Ad4; pd[5]=Ad5; pd[6]=Ad6; pd[7]=Ad7;
        pi[0]=Ai0; pi[1]=Ai1; pi[2]=Ai2; pi[3]=Ai3; pi[4]=Ai4; pi[5]=Ai5; pi[6]=Ai6; pi[7]=Ai7;
    }
    {
        float* pd = partd + ((size_t)q1 * SPLIT + sp) * KNN;
        int*   pi = parti + ((size_t)q1 * SPLIT + sp) * KNN;
        pd[0]=Bd0; pd[1]=Bd1; pd[2]=Bd2; pd[3]=Bd3; pd[4]=Bd4; pd[5]=Bd5; pd[6]=Bd6; pd[7]=Bd7;
        pi[0]=Bi0; pi[1]=Bi1; pi[2]=Bi2; pi[3]=Bi3; pi[4]=Bi4; pi[5]=Bi5; pi[6]=Bi6; pi[7]=Bi7;
    }
}

// ---------------------------------------------------------------------------
// kernel 2: merge SPLIT partial top-8 lists (ascending split order -> stable)
// ---------------------------------------------------------------------------
__global__ __launch_bounds__(256, 2) void k_merge2(
    const float* __restrict__ partd, const int* __restrict__ parti,
    int* __restrict__ knn_idx)
{
    const int q = blockIdx.x * 256 + threadIdx.x;
    const float* pd = partd + (size_t)q * SPLIT * KNN;
    const int*   pi = parti + (size_t)q * SPLIT * KNN;

    TKDECL(M);
#pragma unroll
    for (int t = 0; t < SPLIT * KNN; ++t) {
        const float d = pd[t];
        const int   i = pi[t];
        TKINS(M, d, i);
    }
    int* ko = knn_idx + (size_t)q * KNN;
    ko[0]=Mi0; ko[1]=Mi1; ko[2]=Mi2; ko[3]=Mi3; ko[4]=Mi4; ko[5]=Mi5; ko[6]=Mi6; ko[7]=Mi7;
}

// ---------------------------------------------------------------------------
// kernel 3: MLP — R7 structure (4 waves share one w1s copy, one cross-wave
// barrier, per-wave private inbuf, prefetch pipeline) but launch_bounds
// relaxed to (256,2): R7's (256,4) capped VGPR at 128 < the ~150 needed and
// spilled 471 MB/dispatch to scratch (458 µs). With cap=256 the allocator
// fits the working set; occupancy lands reg-limited at ~3 waves/SIMD.
// ---------------------------------------------------------------------------
#define ACC4(h, wv, iv) \
    h = fmaf((wv).x, (iv).x, h); h = fmaf((wv).y, (iv).y, h); \
    h = fmaf((wv).z, (iv).z, h); h = fmaf((wv).w, (iv).w, h)

#define DOT17(h, ivr) do { \
    ACC4(h, w0,  (ivr)[0]);  ACC4(h, w1,  (ivr)[1]);  ACC4(h, w2,  (ivr)[2]); \
    ACC4(h, w3,  (ivr)[3]);  ACC4(h, w4,  (ivr)[4]);  ACC4(h, w5,  (ivr)[5]); \
    ACC4(h, w6,  (ivr)[6]);  ACC4(h, w7,  (ivr)[7]);  ACC4(h, w8,  (ivr)[8]); \
    ACC4(h, w9,  (ivr)[9]);  ACC4(h, w10, (ivr)[10]); ACC4(h, w11, (ivr)[11]); \
    ACC4(h, w12, (ivr)[12]); ACC4(h, w13, (ivr)[13]); ACC4(h, w14, (ivr)[14]); \
    ACC4(h, w15, (ivr)[15]); ACC4(h, w16, (ivr)[16]); \
} while (0)

#define BFLY(p) \
    p += __shfl_xor(p, 32, 64); p += __shfl_xor(p, 16, 64); \
    p += __shfl_xor(p,  8, 64); p += __shfl_xor(p,  4, 64); \
    p += __shfl_xor(p,  2, 64); p += __shfl_xor(p,  1, 64)

#define L2RED(hk, a0, a1, a2) do { \
    float hv_ = (hk); hv_ = hv_ >= 0.f ? hv_ : 0.1f * hv_; \
    float p0_ = w2a * hv_, p1_ = w2b * hv_, p2_ = w2c * hv_; \
    BFLY(p0_); BFLY(p1_); BFLY(p2_); \
    a0 = p0_ + b20; a1 = p1_ + b21; a2 = p2_ + b22; \
} while (0)

#define SMAX8(sa, sb, sc, sd, se, sf, sg, sh, CH, res) do { \
    const float m_ = fmaxf(fmaxf(fmaxf(sa, sb), fmaxf(sc, sd)), \
                           fmaxf(fmaxf(se, sf), fmaxf(sg, sh))); \
    const float e0_ = __expf(sa - m_), e1_ = __expf(sb - m_); \
    const float e2_ = __expf(sc - m_), e3_ = __expf(sd - m_); \
    const float e4_ = __expf(se - m_), e5_ = __expf(sf - m_); \
    const float e6_ = __expf(sg - m_), e7_ = __expf(sh - m_); \
    const float S_ = ((e0_ + e1_) + (e2_ + e3_)) + ((e4_ + e5_) + (e6_ + e7_)); \
    float acc_ = e0_ * flf[0 * 4 + CH]; \
    acc_ = fmaf(e1_, flf[1 * 4 + CH], acc_); acc_ = fmaf(e2_, flf[2 * 4 + CH], acc_); \
    acc_ = fmaf(e3_, flf[3 * 4 + CH], acc_); acc_ = fmaf(e4_, flf[4 * 4 + CH], acc_); \
    acc_ = fmaf(e5_, flf[5 * 4 + CH], acc_); acc_ = fmaf(e6_, flf[6 * 4 + CH], acc_); \
    acc_ = fmaf(e7_, flf[7 * 4 + CH], acc_); \
    res = acc_ / S_; \
} while (0)

#define MLP_STEP(IT) do { \
    const int n_ = n0 + (IT); \
    __builtin_amdgcn_wave_barrier();  /* WAR: prev-iter reads precede writes */ \
    float4* drow = (float4*)(inw + k * 68); \
    drow[p * 2] = g0; drow[p * 2 + 1] = g1; \
    if (p == 0) { \
        inw[k * 68 + 64] = axv.x - qx; inw[k * 68 + 65] = axv.y - qy; \
        inw[k * 68 + 66] = axv.z - qz; inw[k * 68 + 67] = 0.f; \
    } \
    if (p == 1) flbuf[wave][k] = flv; \
    __builtin_amdgcn_wave_barrier();  /* RAW: writes precede this iter's reads */ \
    if ((IT) < 7) {   /* prefetch next query's gather under this compute */ \
        const int idn_ = idnext; \
        const float4* fr_ = (const float4*)(feat1T + (size_t)(base + idn_) * CF); \
        g0 = fr_[p * 2]; g1 = fr_[p * 2 + 1]; \
        axv = aux4[base + idn_]; flv = flow4[base + idn_]; \
        qx = xyz2[(b * 3 + 0) * N2 + n_ + 1]; \
        qy = xyz2[(b * 3 + 1) * N2 + n_ + 1]; \
        qz = xyz2[(b * 3 + 2) * N2 + n_ + 1]; \
        if ((IT) < 6) idnext = knn_idx[(size_t)(q0 + (IT) + 2) * KNN + k]; \
    } \
    float s00, s01, s02, s03, s04, s05, s06, s07; \
    float s10, s11, s12, s13, s14, s15, s16, s17; \
    float s20, s21, s22, s23, s24, s25, s26, s27; \
    { float h = b1v; DOT17(h, ((const float4*)(inw + 0 * 68))); L2RED(h, s00, s10, s20); } \
    { float h = b1v; DOT17(h, ((const float4*)(inw + 1 * 68))); L2RED(h, s01, s11, s21); } \
    { float h = b1v; DOT17(h, ((const float4*)(inw + 2 * 68))); L2RED(h, s02, s12, s22); } \
    { float h = b1v; DOT17(h, ((const float4*)(inw + 3 * 68))); L2RED(h, s03, s13, s23); } \
    { float h = b1v; DOT17(h, ((const float4*)(inw + 4 * 68))); L2RED(h, s04, s14, s24); } \
    { float h = b1v; DOT17(h, ((const float4*)(inw + 5 * 68))); L2RED(h, s05, s15, s25); } \
    { float h = b1v; DOT17(h, ((const float4*)(inw + 6 * 68))); L2RED(h, s06, s16, s26); } \
    { float h = b1v; DOT17(h, ((const float4*)(inw + 7 * 68))); L2RED(h, s07, s17, s27); } \
    float res0, res1, res2; \
    SMAX8(s00, s01, s02, s03, s04, s05, s06, s07, 0, res0); \
    SMAX8(s10, s11, s12, s13, s14, s15, s16, s17, 1, res1); \
    SMAX8(s20, s21, s22, s23, s24, s25, s26, s27, 2, res2); \
    const float resv = lane == 0 ? res0 : (lane == 1 ? res1 : res2); \
    if (lane < 3) out[((size_t)(b * 3 + lane)) * N2 + n_] = resv; \
} while (0)

__global__ __launch_bounds__(256, 2) void k_mlp3(
    const float* __restrict__ feat1T, const float4* __restrict__ aux4,
    const float4* __restrict__ flow4, const int* __restrict__ knn_idx,
    const float* __restrict__ xyz2,
    const float* __restrict__ W1, const float* __restrict__ b1,
    const float* __restrict__ W2, const float* __restrict__ b2,
    float* __restrict__ out)
{
    __shared__ __align__(16) float w1s[64 * 68];     // 17.0 KiB, shared by 4 waves
    __shared__ __align__(16) float inbuf[4][8][68];  //  8.5 KiB, private per wave
    __shared__ __align__(16) float4 flbuf[4][8];     //  0.5 KiB, private per wave

    const int tid  = threadIdx.x;
    const int wave = tid >> 6, lane = tid & 63;

    for (int t = tid; t < 64 * 67; t += 256) {
        const int o = t / 67, c = t - o * 67;
        w1s[o * 68 + c] = W1[t];
    }
    if (tid < 64) w1s[tid * 68 + 67] = 0.f;

    const float b1v = b1[lane];
    const float w2a = W2[lane], w2b = W2[64 + lane], w2c = W2[128 + lane];
    const float b20 = b2[0], b21 = b2[1], b22 = b2[2];
    __syncthreads();   // the ONLY cross-wave barrier

    const float4* wr = (const float4*)&w1s[lane * 68];
    const float4 w0 = wr[0],  w1 = wr[1],  w2 = wr[2],  w3 = wr[3];
    const float4 w4 = wr[4],  w5 = wr[5],  w6 = wr[6],  w7 = wr[7];
    const float4 w8 = wr[8],  w9 = wr[9],  w10 = wr[10], w11 = wr[11];
    const float4 w12 = wr[12], w13 = wr[13], w14 = wr[14], w15 = wr[15];
    const float4 w16 = wr[16];

    const int k = lane >> 3, p = lane & 7;
    float* inw = &inbuf[wave][0][0];
    const float* flf = (const float*)&flbuf[wave][0];

    const int q0   = blockIdx.x * 32 + wave * 8;   // 8 queries per wave
    const int b    = q0 >> 14;                      // uniform (32 | 16384)
    const int base = b * N1;
    const int n0   = q0 & (N2 - 1);

    const int id0v = knn_idx[(size_t)q0 * KNN + k];
    int idnext     = knn_idx[(size_t)(q0 + 1) * KNN + k];

    const float4* fr0 = (const float4*)(feat1T + (size_t)(base + id0v) * CF);
    float4 g0 = fr0[p * 2], g1 = fr0[p * 2 + 1];
    float4 axv = aux4[base + id0v];
    float4 flv = flow4[base + id0v];
    float qx = xyz2[(b * 3 + 0) * N2 + n0];
    float qy = xyz2[(b * 3 + 1) * N2 + n0];
    float qz = xyz2[(b * 3 + 2) * N2 + n0];

    MLP_STEP(0);
    MLP_STEP(1);
    MLP_STEP(2);
    MLP_STEP(3);
    MLP_STEP(4);
    MLP_STEP(5);
    MLP_STEP(6);
    MLP_STEP(7);
}

// ---------------------------------------------------------------------------
extern "C" void kernel_launch(void* const* d_in, const int* in_sizes, int n_in,
                              void* d_out, int out_size, void* d_ws, size_t ws_size,
                              hipStream_t stream)
{
    const float* xyz1  = (const float*)d_in[0];
    const float* xyz2  = (const float*)d_in[1];
    const float* feat1 = (const float*)d_in[2];
    const float* flow  = (const float*)d_in[3];
    const float* W1    = (const float*)d_in[4];
    const float* b1    = (const float*)d_in[5];
    const float* W2    = (const float*)d_in[6];
    const float* b2    = (const float*)d_in[7];
    float* out = (float*)d_out;

    char* ws = (char*)d_ws;
    float*  feat1T  = (float*)(ws);                                   // 2 MiB
    float4* aux4    = (float4*)(ws + (2u << 20));                     // 128 KiB
    float4* flow4   = (float4*)(ws + (2u << 20) + (128u << 10));      // 128 KiB
    int*    knn_idx = (int*)  (ws + (2u << 20) + (256u << 10));       // 1 MiB
    float*  partd   = (float*)(ws + (3u << 20) + (256u << 10));       // 8 MiB
    int*    parti   = (int*)  (ws + (11u << 20) + (256u << 10));      // 8 MiB

    hipLaunchKernelGGL(k_pack, dim3(N1 / 64, NB), dim3(256), 0, stream,
                       xyz1, feat1, flow, feat1T, aux4, flow4);
    hipLaunchKernelGGL(k_knn4, dim3(NB * N2 / 512, SPLIT), dim3(256), 0, stream,
                       xyz1, xyz2, partd, parti);
    hipLaunchKernelGGL(k_merge2, dim3(NB * N2 / 256), dim3(256), 0, stream,
                       partd, parti, knn_idx);
    hipLaunchKernelGGL(k_mlp3, dim3(NB * N2 / 32), dim3(256), 0, stream,
                       feat1T, aux4, flow4, knn_idx, xyz2, W1, b1, W2, b2, out);
}

// Round 9
// 320.040 us; speedup vs baseline: 1.9306x; 1.0810x over previous
//
#include <hip/hip_runtime.h>
#include <cstdint>
#include <cstddef>

#define NB    2
#define N1    4096
#define N2    16384
#define CF    64
#define KNN   8

// ---------------------------------------------------------------------------
// Scalarized stable top-8 insert (merge kernel): strict <, descending update
// order reading pre-update values -> lower index wins ties (= top_k).
// ---------------------------------------------------------------------------
#define TKDECL(P) \
    float P##d0=INFINITY,P##d1=INFINITY,P##d2=INFINITY,P##d3=INFINITY, \
          P##d4=INFINITY,P##d5=INFINITY,P##d6=INFINITY,P##d7=INFINITY; \
    int   P##i0=0,P##i1=0,P##i2=0,P##i3=0,P##i4=0,P##i5=0,P##i6=0,P##i7=0

#define TKINS(P, dv, ix) do { \
    const bool c0_ = (dv) < P##d0, c1_ = (dv) < P##d1, c2_ = (dv) < P##d2, c3_ = (dv) < P##d3; \
    const bool c4_ = (dv) < P##d4, c5_ = (dv) < P##d5, c6_ = (dv) < P##d6, c7_ = (dv) < P##d7; \
    P##d7 = c6_ ? P##d6 : (c7_ ? (dv) : P##d7);  P##i7 = c6_ ? P##i6 : (c7_ ? (ix) : P##i7); \
    P##d6 = c5_ ? P##d5 : (c6_ ? (dv) : P##d6);  P##i6 = c5_ ? P##i5 : (c6_ ? (ix) : P##i6); \
    P##d5 = c4_ ? P##d4 : (c5_ ? (dv) : P##d5);  P##i5 = c4_ ? P##i4 : (c5_ ? (ix) : P##i5); \
    P##d4 = c3_ ? P##d3 : (c4_ ? (dv) : P##d4);  P##i4 = c3_ ? P##i3 : (c4_ ? (ix) : P##i4); \
    P##d3 = c2_ ? P##d2 : (c3_ ? (dv) : P##d3);  P##i3 = c2_ ? P##i2 : (c3_ ? (ix) : P##i3); \
    P##d2 = c1_ ? P##d1 : (c2_ ? (dv) : P##d2);  P##i2 = c1_ ? P##i1 : (c2_ ? (ix) : P##i2); \
    P##d1 = c0_ ? P##d0 : (c1_ ? (dv) : P##d1);  P##i1 = c0_ ? P##i0 : (c1_ ? (ix) : P##i1); \
    P##d0 = c0_ ? (dv) : P##d0;                  P##i0 = c0_ ? (ix) : P##i0; \
} while (0)

// ---------------------------------------------------------------------------
// kernel 0: transpose feat1 [B,C,N1] -> feat1T [B,N1,C]; pack xyz1/flow float4
// ---------------------------------------------------------------------------
__global__ __launch_bounds__(256, 2) void k_pack(
    const float* __restrict__ xyz1, const float* __restrict__ feat1,
    const float* __restrict__ flow,
    float* __restrict__ feat1T, float4* __restrict__ aux4,
    float4* __restrict__ flow4)
{
    __shared__ float tile[64][65];
    const int b  = blockIdx.y;
    const int n0 = blockIdx.x * 64;
    const int tid = threadIdx.x;
    const int nl = tid & 63, cq = tid >> 6;

#pragma unroll
    for (int r = 0; r < 16; ++r) {
        const int c = r * 4 + cq;
        tile[c][nl] = feat1[((size_t)(b * CF + c)) * N1 + n0 + nl];
    }
    __syncthreads();
#pragma unroll
    for (int r = 0; r < 16; ++r) {
        const int nn = r * 4 + cq;
        feat1T[((size_t)(b * N1 + n0 + nn)) * CF + nl] = tile[nl][nn];
    }
    if (tid < 64) {
        const int n = n0 + tid;
        const float x = xyz1[(b * 3 + 0) * N1 + n];
        const float y = xyz1[(b * 3 + 1) * N1 + n];
        const float z = xyz1[(b * 3 + 2) * N1 + n];
        aux4[b * N1 + n] = make_float4(x, y, z, 0.f);
        const float fx = flow[(b * 3 + 0) * N1 + n];
        const float fy = flow[(b * 3 + 1) * N1 + n];
        const float fz = flow[(b * 3 + 2) * N1 + n];
        flow4[b * N1 + n] = make_float4(fx, fy, fz, 0.f);
    }
}

// ---------------------------------------------------------------------------
// kernel 1: partial KNN — QPT=2, branchless, med3 distance network; SPLIT as
// template param (16 -> 4 blocks/CU = 16 waves/CU vs 8 -> 2 blocks/CU; R8
// showed VALUBusy 83% / Occ 17.7% at SPLIT=8 — grid-limited latency hiding).
// Distance replicates reference fp32 rounding exactly:
// d = (q2+t2) - (qt+qt), qt = ((qx*tx+qy*ty)+qz*tz), all _rn.
// ---------------------------------------------------------------------------
template <int SPLIT_>
__global__ __launch_bounds__(256, 2) void k_knn4t(
    const float* __restrict__ xyz1, const float* __restrict__ xyz2,
    float* __restrict__ partd, int* __restrict__ parti)
{
    constexpr int NS_ = N1 / SPLIT_;
    __shared__ float4 pts[NS_];  // {x, y, z, t2}
    const int sp  = blockIdx.y;
    const int tid = threadIdx.x;
    const int q0  = blockIdx.x * 512 + tid;
    const int q1  = q0 + 256;
    const int b   = q0 >> 14;    // uniform per block (512 | 16384)

    for (int t = tid; t < NS_; t += 256) {
        const int jg = sp * NS_ + t;
        const float x = xyz1[(b * 3 + 0) * N1 + jg];
        const float y = xyz1[(b * 3 + 1) * N1 + jg];
        const float z = xyz1[(b * 3 + 2) * N1 + jg];
        const float t2 = __fadd_rn(__fadd_rn(__fmul_rn(x, x), __fmul_rn(y, y)),
                                   __fmul_rn(z, z));
        pts[t] = make_float4(x, y, z, t2);
    }
    __syncthreads();

    const int n0 = q0 & (N2 - 1), n1 = n0 + 256;
    const float ax = xyz2[(b * 3 + 0) * N2 + n0];
    const float ay = xyz2[(b * 3 + 1) * N2 + n0];
    const float az = xyz2[(b * 3 + 2) * N2 + n0];
    const float a2 = __fadd_rn(__fadd_rn(__fmul_rn(ax, ax), __fmul_rn(ay, ay)),
                               __fmul_rn(az, az));
    const float cx = xyz2[(b * 3 + 0) * N2 + n1];
    const float cy = xyz2[(b * 3 + 1) * N2 + n1];
    const float cz = xyz2[(b * 3 + 2) * N2 + n1];
    const float c2 = __fadd_rn(__fadd_rn(__fmul_rn(cx, cx), __fmul_rn(cy, cy)),
                               __fmul_rn(cz, cz));

    float Ad0=INFINITY,Ad1=INFINITY,Ad2=INFINITY,Ad3=INFINITY,
          Ad4=INFINITY,Ad5=INFINITY,Ad6=INFINITY,Ad7=INFINITY;
    int   Ai0=0,Ai1=0,Ai2=0,Ai3=0,Ai4=0,Ai5=0,Ai6=0,Ai7=0;
    float Bd0=INFINITY,Bd1=INFINITY,Bd2=INFINITY,Bd3=INFINITY,
          Bd4=INFINITY,Bd5=INFINITY,Bd6=INFINITY,Bd7=INFINITY;
    int   Bi0=0,Bi1=0,Bi2=0,Bi3=0,Bi4=0,Bi5=0,Bi6=0,Bi7=0;

#pragma unroll 4
    for (int j = 0; j < NS_; ++j) {
        const float4 p = pts[j];
        const int idx = sp * NS_ + j;

        const float qtA = __fadd_rn(
            __fadd_rn(__fmul_rn(ax, p.x), __fmul_rn(ay, p.y)),
            __fmul_rn(az, p.z));
        const float dA = __fsub_rn(__fadd_rn(a2, p.w), __fadd_rn(qtA, qtA));
        const float qtB = __fadd_rn(
            __fadd_rn(__fmul_rn(cx, p.x), __fmul_rn(cy, p.y)),
            __fmul_rn(cz, p.z));
        const float dB = __fsub_rn(__fadd_rn(c2, p.w), __fadd_rn(qtB, qtB));

        {
            const float m0 = fminf(dA, Ad0);
            const float m1 = __builtin_amdgcn_fmed3f(dA, Ad0, Ad1);
            const float m2 = __builtin_amdgcn_fmed3f(dA, Ad1, Ad2);
            const float m3 = __builtin_amdgcn_fmed3f(dA, Ad2, Ad3);
            const float m4 = __builtin_amdgcn_fmed3f(dA, Ad3, Ad4);
            const float m5 = __builtin_amdgcn_fmed3f(dA, Ad4, Ad5);
            const float m6 = __builtin_amdgcn_fmed3f(dA, Ad5, Ad6);
            const float m7 = __builtin_amdgcn_fmed3f(dA, Ad6, Ad7);
            const bool a0 = dA < Ad0, a1 = dA < Ad1, a2c = dA < Ad2, a3 = dA < Ad3;
            const bool a4 = dA < Ad4, a5 = dA < Ad5, a6 = dA < Ad6, a7 = dA < Ad7;
            Ai7 = a6 ? Ai6 : (a7 ? idx : Ai7);
            Ai6 = a5 ? Ai5 : (a6 ? idx : Ai6);
            Ai5 = a4 ? Ai4 : (a5 ? idx : Ai5);
            Ai4 = a3 ? Ai3 : (a4 ? idx : Ai4);
            Ai3 = a2c ? Ai2 : (a3 ? idx : Ai3);
            Ai2 = a1 ? Ai1 : (a2c ? idx : Ai2);
            Ai1 = a0 ? Ai0 : (a1 ? idx : Ai1);
            Ai0 = a0 ? idx : Ai0;
            Ad0=m0; Ad1=m1; Ad2=m2; Ad3=m3; Ad4=m4; Ad5=m5; Ad6=m6; Ad7=m7;
        }
        {
            const float m0 = fminf(dB, Bd0);
            const float m1 = __builtin_amdgcn_fmed3f(dB, Bd0, Bd1);
            const float m2 = __builtin_amdgcn_fmed3f(dB, Bd1, Bd2);
            const float m3 = __builtin_amdgcn_fmed3f(dB, Bd2, Bd3);
            const float m4 = __builtin_amdgcn_fmed3f(dB, Bd3, Bd4);
            const float m5 = __builtin_amdgcn_fmed3f(dB, Bd4, Bd5);
            const float m6 = __builtin_amdgcn_fmed3f(dB, Bd5, Bd6);
            const float m7 = __builtin_amdgcn_fmed3f(dB, Bd6, Bd7);
            const bool a0 = dB < Bd0, a1 = dB < Bd1, a2c = dB < Bd2, a3 = dB < Bd3;
            const bool a4 = dB < Bd4, a5 = dB < Bd5, a6 = dB < Bd6, a7 = dB < Bd7;
            Bi7 = a6 ? Bi6 : (a7 ? idx : Bi7);
            Bi6 = a5 ? Bi5 : (a6 ? idx : Bi6);
            Bi5 = a4 ? Bi4 : (a5 ? idx : Bi5);
            Bi4 = a3 ? Bi3 : (a4 ? idx : Bi4);
            Bi3 = a2c ? Bi2 : (a3 ? idx : Bi3);
            Bi2 = a1 ? Bi1 : (a2c ? idx : Bi2);
            Bi1 = a0 ? Bi0 : (a1 ? idx : Bi1);
            Bi0 = a0 ? idx : Bi0;
            Bd0=m0; Bd1=m1; Bd2=m2; Bd3=m3; Bd4=m4; Bd5=m5; Bd6=m6; Bd7=m7;
        }
    }

    {
        float* pd = partd + ((size_t)q0 * SPLIT_ + sp) * KNN;
        int*   pi = parti + ((size_t)q0 * SPLIT_ + sp) * KNN;
        pd[0]=Ad0; pd[1]=Ad1; pd[2]=Ad2; pd[3]=Ad3; pd[4]=Ad4; pd[5]=Ad5; pd[6]=Ad6; pd[7]=Ad7;
        pi[0]=Ai0; pi[1]=Ai1; pi[2]=Ai2; pi[3]=Ai3; pi[4]=Ai4; pi[5]=Ai5; pi[6]=Ai6; pi[7]=Ai7;
    }
    {
        float* pd = partd + ((size_t)q1 * SPLIT_ + sp) * KNN;
        int*   pi = parti + ((size_t)q1 * SPLIT_ + sp) * KNN;
        pd[0]=Bd0; pd[1]=Bd1; pd[2]=Bd2; pd[3]=Bd3; pd[4]=Bd4; pd[5]=Bd5; pd[6]=Bd6; pd[7]=Bd7;
        pi[0]=Bi0; pi[1]=Bi1; pi[2]=Bi2; pi[3]=Bi3; pi[4]=Bi4; pi[5]=Bi5; pi[6]=Bi6; pi[7]=Bi7;
    }
}

// ---------------------------------------------------------------------------
// kernel 2: merge SPLIT partial top-8 lists (ascending split order -> stable)
// ---------------------------------------------------------------------------
template <int SPLIT_>
__global__ __launch_bounds__(256, 2) void k_merge2t(
    const float* __restrict__ partd, const int* __restrict__ parti,
    int* __restrict__ knn_idx)
{
    const int q = blockIdx.x * 256 + threadIdx.x;
    const float* pd = partd + (size_t)q * SPLIT_ * KNN;
    const int*   pi = parti + (size_t)q * SPLIT_ * KNN;

    TKDECL(M);
#pragma unroll
    for (int t = 0; t < SPLIT_ * KNN; ++t) {
        const float d = pd[t];
        const int   i = pi[t];
        TKINS(M, d, i);
    }
    int* ko = knn_idx + (size_t)q * KNN;
    ko[0]=Mi0; ko[1]=Mi1; ko[2]=Mi2; ko[3]=Mi3; ko[4]=Mi4; ko[5]=Mi5; ko[6]=Mi6; ko[7]=Mi7;
}

// ---------------------------------------------------------------------------
// kernel 3: MLP — R8 structure, but layer-2 reduction via DPP (VALU-only)
// instead of __shfl_xor butterflies (was 144 ds_permute/query in 6-deep
// dependent chains — the suspected latency/throughput tax).
// wave_sum_dpp: row_shr 1/2/4/8 (row sums into lane 15 of each row16),
// row_bcast:15 (rows 1,3), row_bcast:31 (rows 2,3) -> lane 63 = full sum.
// ---------------------------------------------------------------------------
__device__ __forceinline__ float wave_sum_dpp(float x) {
    int t;
    t = __builtin_amdgcn_update_dpp(0, __float_as_int(x), 0x111, 0xF, 0xF, false);
    x += __int_as_float(t);
    t = __builtin_amdgcn_update_dpp(0, __float_as_int(x), 0x112, 0xF, 0xF, false);
    x += __int_as_float(t);
    t = __builtin_amdgcn_update_dpp(0, __float_as_int(x), 0x114, 0xF, 0xF, false);
    x += __int_as_float(t);
    t = __builtin_amdgcn_update_dpp(0, __float_as_int(x), 0x118, 0xF, 0xF, false);
    x += __int_as_float(t);
    t = __builtin_amdgcn_update_dpp(0, __float_as_int(x), 0x142, 0xA, 0xF, false);
    x += __int_as_float(t);
    t = __builtin_amdgcn_update_dpp(0, __float_as_int(x), 0x143, 0xC, 0xF, false);
    x += __int_as_float(t);
    return __int_as_float(__builtin_amdgcn_readlane(__float_as_int(x), 63));
}

#define ACC4(h, wv, iv) \
    h = fmaf((wv).x, (iv).x, h); h = fmaf((wv).y, (iv).y, h); \
    h = fmaf((wv).z, (iv).z, h); h = fmaf((wv).w, (iv).w, h)

#define DOT17(h, ivr) do { \
    ACC4(h, w0,  (ivr)[0]);  ACC4(h, w1,  (ivr)[1]);  ACC4(h, w2,  (ivr)[2]); \
    ACC4(h, w3,  (ivr)[3]);  ACC4(h, w4,  (ivr)[4]);  ACC4(h, w5,  (ivr)[5]); \
    ACC4(h, w6,  (ivr)[6]);  ACC4(h, w7,  (ivr)[7]);  ACC4(h, w8,  (ivr)[8]); \
    ACC4(h, w9,  (ivr)[9]);  ACC4(h, w10, (ivr)[10]); ACC4(h, w11, (ivr)[11]); \
    ACC4(h, w12, (ivr)[12]); ACC4(h, w13, (ivr)[13]); ACC4(h, w14, (ivr)[14]); \
    ACC4(h, w15, (ivr)[15]); ACC4(h, w16, (ivr)[16]); \
} while (0)

#define L2RED(hk, a0, a1, a2) do { \
    float hv_ = (hk); hv_ = hv_ >= 0.f ? hv_ : 0.1f * hv_; \
    a0 = wave_sum_dpp(w2a * hv_) + b20; \
    a1 = wave_sum_dpp(w2b * hv_) + b21; \
    a2 = wave_sum_dpp(w2c * hv_) + b22; \
} while (0)

#define SMAX8(sa, sb, sc, sd, se, sf, sg, sh, CH, res) do { \
    const float m_ = fmaxf(fmaxf(fmaxf(sa, sb), fmaxf(sc, sd)), \
                           fmaxf(fmaxf(se, sf), fmaxf(sg, sh))); \
    const float e0_ = __expf(sa - m_), e1_ = __expf(sb - m_); \
    const float e2_ = __expf(sc - m_), e3_ = __expf(sd - m_); \
    const float e4_ = __expf(se - m_), e5_ = __expf(sf - m_); \
    const float e6_ = __expf(sg - m_), e7_ = __expf(sh - m_); \
    const float S_ = ((e0_ + e1_) + (e2_ + e3_)) + ((e4_ + e5_) + (e6_ + e7_)); \
    float acc_ = e0_ * flf[0 * 4 + CH]; \
    acc_ = fmaf(e1_, flf[1 * 4 + CH], acc_); acc_ = fmaf(e2_, flf[2 * 4 + CH], acc_); \
    acc_ = fmaf(e3_, flf[3 * 4 + CH], acc_); acc_ = fmaf(e4_, flf[4 * 4 + CH], acc_); \
    acc_ = fmaf(e5_, flf[5 * 4 + CH], acc_); acc_ = fmaf(e6_, flf[6 * 4 + CH], acc_); \
    acc_ = fmaf(e7_, flf[7 * 4 + CH], acc_); \
    res = acc_ / S_; \
} while (0)

#define MLP_STEP(IT) do { \
    const int n_ = n0 + (IT); \
    __builtin_amdgcn_wave_barrier();  /* WAR: prev-iter reads precede writes */ \
    float4* drow = (float4*)(inw + k * 68); \
    drow[p * 2] = g0; drow[p * 2 + 1] = g1; \
    if (p == 0) { \
        inw[k * 68 + 64] = axv.x - qx; inw[k * 68 + 65] = axv.y - qy; \
        inw[k * 68 + 66] = axv.z - qz; inw[k * 68 + 67] = 0.f; \
    } \
    if (p == 1) flbuf[wave][k] = flv; \
    __builtin_amdgcn_wave_barrier();  /* RAW: writes precede this iter's reads */ \
    if ((IT) < 7) {   /* prefetch next query's gather under this compute */ \
        const int idn_ = idnext; \
        const float4* fr_ = (const float4*)(feat1T + (size_t)(base + idn_) * CF); \
        g0 = fr_[p * 2]; g1 = fr_[p * 2 + 1]; \
        axv = aux4[base + idn_]; flv = flow4[base + idn_]; \
        qx = xyz2[(b * 3 + 0) * N2 + n_ + 1]; \
        qy = xyz2[(b * 3 + 1) * N2 + n_ + 1]; \
        qz = xyz2[(b * 3 + 2) * N2 + n_ + 1]; \
        if ((IT) < 6) idnext = knn_idx[(size_t)(q0 + (IT) + 2) * KNN + k]; \
    } \
    float s00, s01, s02, s03, s04, s05, s06, s07; \
    float s10, s11, s12, s13, s14, s15, s16, s17; \
    float s20, s21, s22, s23, s24, s25, s26, s27; \
    { float h = b1v; DOT17(h, ((const float4*)(inw + 0 * 68))); L2RED(h, s00, s10, s20); } \
    { float h = b1v; DOT17(h, ((const float4*)(inw + 1 * 68))); L2RED(h, s01, s11, s21); } \
    { float h = b1v; DOT17(h, ((const float4*)(inw + 2 * 68))); L2RED(h, s02, s12, s22); } \
    { float h = b1v; DOT17(h, ((const float4*)(inw + 3 * 68))); L2RED(h, s03, s13, s23); } \
    { float h = b1v; DOT17(h, ((const float4*)(inw + 4 * 68))); L2RED(h, s04, s14, s24); } \
    { float h = b1v; DOT17(h, ((const float4*)(inw + 5 * 68))); L2RED(h, s05, s15, s25); } \
    { float h = b1v; DOT17(h, ((const float4*)(inw + 6 * 68))); L2RED(h, s06, s16, s26); } \
    { float h = b1v; DOT17(h, ((const float4*)(inw + 7 * 68))); L2RED(h, s07, s17, s27); } \
    float res0, res1, res2; \
    SMAX8(s00, s01, s02, s03, s04, s05, s06, s07, 0, res0); \
    SMAX8(s10, s11, s12, s13, s14, s15, s16, s17, 1, res1); \
    SMAX8(s20, s21, s22, s23, s24, s25, s26, s27, 2, res2); \
    const float resv = lane == 0 ? res0 : (lane == 1 ? res1 : res2); \
    if (lane < 3) out[((size_t)(b * 3 + lane)) * N2 + n_] = resv; \
} while (0)

__global__ __launch_bounds__(256, 2) void k_mlp4(
    const float* __restrict__ feat1T, const float4* __restrict__ aux4,
    const float4* __restrict__ flow4, const int* __restrict__ knn_idx,
    const float* __restrict__ xyz2,
    const float* __restrict__ W1, const float* __restrict__ b1,
    const float* __restrict__ W2, const float* __restrict__ b2,
    float* __restrict__ out)
{
    __shared__ __align__(16) float w1s[64 * 68];     // 17.0 KiB, shared by 4 waves
    __shared__ __align__(16) float inbuf[4][8][68];  //  8.5 KiB, private per wave
    __shared__ __align__(16) float4 flbuf[4][8];     //  0.5 KiB, private per wave

    const int tid  = threadIdx.x;
    const int wave = tid >> 6, lane = tid & 63;

    for (int t = tid; t < 64 * 67; t += 256) {
        const int o = t / 67, c = t - o * 67;
        w1s[o * 68 + c] = W1[t];
    }
    if (tid < 64) w1s[tid * 68 + 67] = 0.f;

    const float b1v = b1[lane];
    const float w2a = W2[lane], w2b = W2[64 + lane], w2c = W2[128 + lane];
    const float b20 = b2[0], b21 = b2[1], b22 = b2[2];
    __syncthreads();   // the ONLY cross-wave barrier

    const float4* wr = (const float4*)&w1s[lane * 68];
    const float4 w0 = wr[0],  w1 = wr[1],  w2 = wr[2],  w3 = wr[3];
    const float4 w4 = wr[4],  w5 = wr[5],  w6 = wr[6],  w7 = wr[7];
    const float4 w8 = wr[8],  w9 = wr[9],  w10 = wr[10], w11 = wr[11];
    const float4 w12 = wr[12], w13 = wr[13], w14 = wr[14], w15 = wr[15];
    const float4 w16 = wr[16];

    const int k = lane >> 3, p = lane & 7;
    float* inw = &inbuf[wave][0][0];
    const float* flf = (const float*)&flbuf[wave][0];

    const int q0   = blockIdx.x * 32 + wave * 8;   // 8 queries per wave
    const int b    = q0 >> 14;                      // uniform (32 | 16384)
    const int base = b * N1;
    const int n0   = q0 & (N2 - 1);

    const int id0v = knn_idx[(size_t)q0 * KNN + k];
    int idnext     = knn_idx[(size_t)(q0 + 1) * KNN + k];

    const float4* fr0 = (const float4*)(feat1T + (size_t)(base + id0v) * CF);
    float4 g0 = fr0[p * 2], g1 = fr0[p * 2 + 1];
    float4 axv = aux4[base + id0v];
    float4 flv = flow4[base + id0v];
    float qx = xyz2[(b * 3 + 0) * N2 + n0];
    float qy = xyz2[(b * 3 + 1) * N2 + n0];
    float qz = xyz2[(b * 3 + 2) * N2 + n0];

    MLP_STEP(0);
    MLP_STEP(1);
    MLP_STEP(2);
    MLP_STEP(3);
    MLP_STEP(4);
    MLP_STEP(5);
    MLP_STEP(6);
    MLP_STEP(7);
}

// ---------------------------------------------------------------------------
extern "C" void kernel_launch(void* const* d_in, const int* in_sizes, int n_in,
                              void* d_out, int out_size, void* d_ws, size_t ws_size,
                              hipStream_t stream)
{
    const float* xyz1  = (const float*)d_in[0];
    const float* xyz2  = (const float*)d_in[1];
    const float* feat1 = (const float*)d_in[2];
    const float* flow  = (const float*)d_in[3];
    const float* W1    = (const float*)d_in[4];
    const float* b1    = (const float*)d_in[5];
    const float* W2    = (const float*)d_in[6];
    const float* b2    = (const float*)d_in[7];
    float* out = (float*)d_out;

    char* ws = (char*)d_ws;
    float*  feat1T  = (float*)(ws);                                   // 2 MiB
    float4* aux4    = (float4*)(ws + (2u << 20));                     // 128 KiB
    float4* flow4   = (float4*)(ws + (2u << 20) + (128u << 10));      // 128 KiB
    int*    knn_idx = (int*)  (ws + (2u << 20) + (256u << 10));       // 1 MiB
    char*   part0   = ws + (3u << 20) + (256u << 10);

    // SPLIT=16 needs 3.25 + 2*16 = 35.25 MiB of ws; fall back to SPLIT=8.
    const size_t need16 = (size_t)(3u << 20) + (256u << 10) + 2 * (size_t)(16u << 20);

    hipLaunchKernelGGL(k_pack, dim3(N1 / 64, NB), dim3(256), 0, stream,
                       xyz1, feat1, flow, feat1T, aux4, flow4);

    if (ws_size >= need16) {
        float* partd = (float*)part0;
        int*   parti = (int*)(part0 + (size_t)(16u << 20));
        hipLaunchKernelGGL((k_knn4t<16>), dim3(NB * N2 / 512, 16), dim3(256),
                           0, stream, xyz1, xyz2, partd, parti);
        hipLaunchKernelGGL((k_merge2t<16>), dim3(NB * N2 / 256), dim3(256),
                           0, stream, partd, parti, knn_idx);
    } else {
        float* partd = (float*)part0;
        int*   parti = (int*)(part0 + (size_t)(8u << 20));
        hipLaunchKernelGGL((k_knn4t<8>), dim3(NB * N2 / 512, 8), dim3(256),
                           0, stream, xyz1, xyz2, partd, parti);
        hipLaunchKernelGGL((k_merge2t<8>), dim3(NB * N2 / 256), dim3(256),
                           0, stream, partd, parti, knn_idx);
    }

    hipLaunchKernelGGL(k_mlp4, dim3(NB * N2 / 32), dim3(256), 0, stream,
                       feat1T, aux4, flow4, knn_idx, xyz2, W1, b1, W2, b2, out);
}